// Round 8
// baseline (234.428 us; speedup 1.0000x reference)
//
#include <hip/hip_runtime.h>
#include <math.h>

#define NN 200000
#define DD 64
#define BB 4096
#define KK 128
#define WW 20
#define HH 128
#define TPB 256
#define RPB 2    // targets per block; 4 waves/block, 8 blocks/CU

#define INV2PI 0.15915494309189535f

__device__ __forceinline__ float fast_rcp(float x) { return __builtin_amdgcn_rcpf(x); }
__device__ __forceinline__ float fast_rsq(float x) { return __builtin_amdgcn_rsqf(x); }

// DPP cross-lane add: x + dpp_move(x). VALU-speed, no LDS pipe.
template <int CTRL>
__device__ __forceinline__ float dpp_add(float x) {
    int y = __builtin_amdgcn_update_dpp(0, __float_as_int(x), CTRL, 0xF, 0xF, true);
    return x + __int_as_float(y);
}
#define DPP_XOR1  0xB1   // quad_perm [1,0,3,2]
#define DPP_XOR2  0x4E   // quad_perm [2,3,0,1]
#define DPP_HMIRR 0x141  // row_half_mirror (j -> 7-j within 8)
#define DPP_ROR8  0x128  // row_ror:8 (j -> j+8 within row of 16)

// Round 8 = R7's register-resident core with the synchronization domain cut
// in half: 2048 blocks x 256 threads (4 waves), 2 targets/block, 8
// independent blocks per CU. Barriers now couple only 4 waves, and the 8
// co-resident blocks phase-drift freely -- when one parks at a barrier the
// others issue. Per-thread work identical to R7 (8 core passes).
//   start : gathers (1 slot/thread) -> dtg{dt,g,ts,m}; wave 3 runs the whole
//           history aggregation (2 targets x 32 cols x 20 taps); waves 0-1
//           target encodings -> stL + tile.
//   core  : thread=(slot,dim-octet); per target r (x2), per pass (x4):
//           one broadcast b128 of dtg -> 8-dim feature in-lane -> s2/sd via
//           ror8-DPP + shfl_xor(16,32) -> wk in-register -> acc FMA.
//           Slot-tree (xor1/xor2/hmirror DPP) -> part[r][wave][dim].
//   GEMM  : thread=(h, j-half); W float4 straight from L2, each element
//           once per block; partials combined via dead dtg.
// 4 barriers; ~8.2 KB LDS.
__global__ __launch_bounds__(256, 8) void fused(
    const float* __restrict__ adj_time, const float* __restrict__ gc,
    const float* __restrict__ cur_time, const float* __restrict__ neigh_mask,
    const float* __restrict__ hist_feat, const float* __restrict__ hist_time,
    const float* __restrict__ t2v_w, const float* __restrict__ t2v_b,
    const float* __restrict__ node_w, const float* __restrict__ node_b,
    const float* __restrict__ att_w, const float* __restrict__ att_b,
    const float* __restrict__ weight,
    const int* __restrict__ targets, const int* __restrict__ neigh_idx,
    float* __restrict__ out)
{
    const int b0   = blockIdx.x * RPB;
    const int tid  = threadIdx.x;
    const int lane = tid & 63;
    const int wv   = tid >> 6;          // wave id 0..3

    __shared__ float4 dtg[RPB * KK];        // {dt, g, ts, m}; reused as prow   4 KB
    __shared__ float  stL[RPB];             // target att-dot per row
    __shared__ float  part[RPB][4][DD];     // per-(target,wave) agg partials   2 KB
    __shared__ float  tile[RPB * 256];      // feat4 rows                       2 KB

    const float t = cur_time[0];

    // ---- per-lane dim-octet parameters (VGPR-resident, loaded once) ----
    const int dg = lane >> 3;           // dim octet 0..7
    const int d0 = dg * 8;
    float pw[8], pb[8], nw[8], nb[8], aw[8];
    {
        float4 a0 = *(const float4*)(t2v_w + d0),  a1 = *(const float4*)(t2v_w + d0 + 4);
        float4 b0_ = *(const float4*)(t2v_b + d0), b1 = *(const float4*)(t2v_b + d0 + 4);
        float4 c0 = *(const float4*)(node_w + d0), c1 = *(const float4*)(node_w + d0 + 4);
        float4 e0 = *(const float4*)(node_b + d0), e1 = *(const float4*)(node_b + d0 + 4);
        float4 w0 = *(const float4*)(att_w + 64 + d0), w1 = *(const float4*)(att_w + 64 + d0 + 4);
        pw[0]=a0.x*INV2PI; pw[1]=a0.y*INV2PI; pw[2]=a0.z*INV2PI; pw[3]=a0.w*INV2PI;
        pw[4]=a1.x*INV2PI; pw[5]=a1.y*INV2PI; pw[6]=a1.z*INV2PI; pw[7]=a1.w*INV2PI;
        pb[0]=b0_.x*INV2PI; pb[1]=b0_.y*INV2PI; pb[2]=b0_.z*INV2PI; pb[3]=b0_.w*INV2PI;
        pb[4]=b1.x*INV2PI; pb[5]=b1.y*INV2PI; pb[6]=b1.z*INV2PI; pb[7]=b1.w*INV2PI;
        nw[0]=c0.x; nw[1]=c0.y; nw[2]=c0.z; nw[3]=c0.w; nw[4]=c1.x; nw[5]=c1.y; nw[6]=c1.z; nw[7]=c1.w;
        nb[0]=e0.x; nb[1]=e0.y; nb[2]=e0.z; nb[3]=e0.w; nb[4]=e1.x; nb[5]=e1.y; nb[6]=e1.z; nb[7]=e1.w;
        aw[0]=w0.x; aw[1]=w0.y; aw[2]=w0.z; aw[3]=w0.w; aw[4]=w1.x; aw[5]=w1.y; aw[6]=w1.z; aw[7]=w1.w;
    }
    const float ow0 = t2v_w[0], ob0 = t2v_b[0];     // unscaled linear channel
    const float ab  = att_b[0];
    const bool  isd0 = (dg == 0);

    // ---- gathers: one slot per thread (slot = r*128 + k = tid) ----
    {
        const int   idx = neigh_idx[b0 * KK + tid];
        const float m   = neigh_mask[b0 * KK + tid];
        const float at  = adj_time[idx];
        const float g   = gc[idx];
        const float dt  = fabsf(t - at);
        const float ts  = fast_rcp(2.0f * __logf(2.71828182845904523536f + (t - at)));
        dtg[tid] = make_float4(dt, g, ts, m);
    }

    // ---- history aggregation, wave 3, fully self-contained ----
    if (wv == 3) {
        const int r  = lane >> 5;        // 0..1
        const int c4 = lane & 31;        // float4 column
        const float*  ht = hist_time + (size_t)(b0 + r) * WW;
        const float4* hf = (const float4*)(hist_feat + (size_t)(b0 + r) * WW * 128) + c4;
        float4 s4 = make_float4(0.f, 0.f, 0.f, 0.f);
#pragma unroll 4
        for (int w = 0; w < WW; ++w) {
            float  hw = fast_rcp(2.0f * (1.0f + (t - ht[w])));
            float4 v  = hf[w * 32];
            s4.x = fmaf(hw, v.x, s4.x);
            s4.y = fmaf(hw, v.y, s4.y);
            s4.z = fmaf(hw, v.z, s4.z);
            s4.w = fmaf(hw, v.w, s4.w);
        }
        *(float4*)(tile + r * 256 + c4 * 4) = s4;
    }

    // ---- target encoding, wave wv -> target wv (waves 0-1) ----
    if (wv < RPB) {
        int   tg  = targets[b0 + wv];
        float dtT = fabsf(t - adj_time[tg]);
        float gT  = gc[tg];
        float ph  = fmaf(t2v_w[lane], dtT, t2v_b[lane]);
        float cv  = __builtin_amdgcn_cosf(ph * INV2PI);
        float tv_ = (lane == 0) ? ph : cv;
        float f   = fmaxf(tv_ + fmaf(gT, node_w[lane], node_b[lane]), 0.f);
        float ss  = f * f;
#pragma unroll
        for (int off = 32; off; off >>= 1) ss += __shfl_xor(ss, off, 64);
        float invn = fast_rsq(fmaxf(ss, 1e-24f));
        float tfn  = f * invn;
        float sdt  = tfn * att_w[lane];
#pragma unroll
        for (int off = 32; off; off >>= 1) sdt += __shfl_xor(sdt, off, 64);
        if (lane == 0) stL[wv] = sdt;
        tile[wv * 256 + 128 + lane] = tfn;
    }
    __syncthreads();   // A: dtg, stL, hist tile cols ready

    // ---- core: score + aggregation, zero memory in the hot path ----
#pragma unroll
    for (int r = 0; r < RPB; ++r) {
        const float stv = stL[r];                   // uniform broadcast, once/target
        float acc[8] = {0.f, 0.f, 0.f, 0.f, 0.f, 0.f, 0.f, 0.f};
#pragma unroll
        for (int pass = 0; pass < 4; ++pass) {
            const float4 dgw = dtg[r * KK + pass * 32 + wv * 8 + (lane & 7)];
            const float dts = dgw.x, gs = dgw.y, tss = dgw.z, ms = dgw.w;
            float f[8], s2, sd;
            {   // i = 0 (handles the d==0 linear channel on dg==0 lanes)
                float ph  = fmaf(pw[0], dts, pb[0]);
                float cv  = __builtin_amdgcn_cosf(ph);
                float lin = fmaf(ow0, dts, ob0);
                float tv_ = isd0 ? lin : cv;
                float fv  = fmaxf(tv_ + fmaf(gs, nw[0], nb[0]), 0.f);
                f[0] = fv; s2 = fv * fv; sd = fv * aw[0];
            }
#pragma unroll
            for (int i = 1; i < 8; ++i) {
                float ph = fmaf(pw[i], dts, pb[i]);
                float cv = __builtin_amdgcn_cosf(ph);
                float fv = fmaxf(cv + fmaf(gs, nw[i], nb[i]), 0.f);
                f[i] = fv;
                s2 = fmaf(fv, fv, s2);
                sd = fmaf(fv, aw[i], sd);
            }
            // reduce s2/sd over the 8 dim-octets (stride-8 lanes)
            s2 = dpp_add<DPP_ROR8>(s2);
            s2 += __shfl_xor(s2, 16, 64);
            s2 += __shfl_xor(s2, 32, 64);
            sd = dpp_add<DPP_ROR8>(sd);
            sd += __shfl_xor(sd, 16, 64);
            sd += __shfl_xor(sd, 32, 64);
            // wk fully in-register
            float invn = fast_rsq(fmaxf(s2, 1e-24f));
            float sc   = tss + stv + sd * invn + ab;
            sc = (sc > 0.f) ? sc : 0.01f * sc;      // leaky_relu(0.01)
            float wk = sc * ms * invn;
#pragma unroll
            for (int i = 0; i < 8; ++i) acc[i] = fmaf(wk, f[i], acc[i]);
        }
        // slot-tree: sum over 8 consecutive lanes (the 8 slot positions)
#pragma unroll
        for (int i = 0; i < 8; ++i) {
            acc[i] = dpp_add<DPP_XOR1>(acc[i]);
            acc[i] = dpp_add<DPP_XOR2>(acc[i]);
            acc[i] = dpp_add<DPP_HMIRR>(acc[i]);
        }
        if ((lane & 7) == 0) {
#pragma unroll
            for (int i = 0; i < 8; ++i) part[r][wv][d0 + i] = acc[i];
        }
    }
    __syncthreads();   // D: partials ready; dtg dead

    // ---- combine: tile cols 192-255 = sum of 4 wave partials ----
    if (tid < RPB * DD) {
        const int r = tid >> 6, d = tid & 63;
        float s = part[r][0][d] + part[r][1][d] + part[r][2][d] + part[r][3][d];
        tile[r * 256 + 192 + d] = s;
    }
    __syncthreads();   // E: tile complete

    // ---- GEMM: thread = (h, j-half sq); W float4 straight from L2 ----
    const int h  = tid & 127;
    const int sq = tid >> 7;                        // 0..1
    const float4* w4 = (const float4*)weight + h * 64 + sq * 32;
    const int jb = sq * 128;
    float a0 = 0.f, a1 = 0.f;
#pragma unroll 4
    for (int j4 = 0; j4 < 32; ++j4) {
        float4 w  = w4[j4];
        const int jo = jb + j4 * 4;
        float4 f0 = *(const float4*)(tile + 0 * 256 + jo);   // uniform broadcasts
        float4 f1 = *(const float4*)(tile + 1 * 256 + jo);
        a0 += w.x * f0.x + w.y * f0.y + w.z * f0.z + w.w * f0.w;
        a1 += w.x * f1.x + w.y * f1.y + w.z * f1.z + w.w * f1.w;
    }

    // ---- combine 2 sq-partials per (row, h) via dead dtg buffer ----
    float* prow = (float*)dtg;                      // 1024 floats
    prow[(0 * 2 + sq) * 128 + h] = a0;
    prow[(1 * 2 + sq) * 128 + h] = a1;
    __syncthreads();   // F
    {
        const int r2 = tid >> 7;                    // 0..1
        float s = prow[(r2 * 2 + 0) * 128 + h] + prow[(r2 * 2 + 1) * 128 + h];
        out[(size_t)(b0 + r2) * 128 + h] = fmaxf(s, 0.f);
    }
}

extern "C" void kernel_launch(void* const* d_in, const int* in_sizes, int n_in,
                              void* d_out, int out_size, void* d_ws, size_t ws_size,
                              hipStream_t stream) {
    const float* adj_time  = (const float*)d_in[0];
    const float* gc        = (const float*)d_in[1];
    const float* cur_time  = (const float*)d_in[2];
    const float* neigh_mask= (const float*)d_in[3];
    const float* hist_feat = (const float*)d_in[4];
    const float* hist_time = (const float*)d_in[5];
    const float* t2v_w     = (const float*)d_in[6];
    const float* t2v_b     = (const float*)d_in[7];
    const float* node_w    = (const float*)d_in[8];
    const float* node_b    = (const float*)d_in[9];
    const float* att_w     = (const float*)d_in[10];
    const float* att_b     = (const float*)d_in[11];
    const float* weight    = (const float*)d_in[12];
    const int*   targets   = (const int*)d_in[13];
    const int*   neigh_idx = (const int*)d_in[14];

    float* out = (float*)d_out;

    fused<<<BB / RPB, TPB, 0, stream>>>(adj_time, gc, cur_time, neigh_mask,
                                        hist_feat, hist_time, t2v_w, t2v_b,
                                        node_w, node_b, att_w, att_b, weight,
                                        targets, neigh_idx, out);
}

// Round 9
// 165.787 us; speedup vs baseline: 1.4140x; 1.4140x over previous
//
#include <hip/hip_runtime.h>
#include <math.h>

#define NN 200000
#define DD 64
#define BB 4096
#define KK 128
#define WW 20
#define HH 128
#define TPB 256
#define RPB 2    // targets per block; 4 waves/block

#define INV2PI 0.15915494309189535f

__device__ __forceinline__ float fast_rcp(float x) { return __builtin_amdgcn_rcpf(x); }
__device__ __forceinline__ float fast_rsq(float x) { return __builtin_amdgcn_rsqf(x); }

// DPP cross-lane add: x + dpp_move(x). VALU-speed, no LDS pipe.
template <int CTRL>
__device__ __forceinline__ float dpp_add(float x) {
    int y = __builtin_amdgcn_update_dpp(0, __float_as_int(x), CTRL, 0xF, 0xF, true);
    return x + __int_as_float(y);
}
#define DPP_XOR1  0xB1   // quad_perm [1,0,3,2]
#define DPP_XOR2  0x4E   // quad_perm [2,3,0,1]
#define DPP_HMIRR 0x141  // row_half_mirror (j -> 7-j within 8)
#define DPP_ROR8  0x128  // row_ror:8 (j -> j+8 within row of 16)

// Round 9 = round 8 with the spill fixed: __launch_bounds__(256, 6) gives an
// ~85-VGPR cap (the core needs ~40-48; R8's (256,8) forced 32 VGPR and spilled
// 83 dwords/thread -> 174 MB of scratch writes, the entire regression).
// 2048 blocks x 256 threads (4 waves), 2 targets/block, 6 blocks/CU:
// small barrier domains + independent per-block phase drift, no spill.
//   start : gathers (1 slot/thread) -> dtg{dt,g,ts,m}; wave 3 runs the whole
//           history aggregation; waves 0-1 target encodings -> stL + tile.
//   core  : thread=(slot,dim-octet); per target r (x2), per pass (x4):
//           one broadcast b128 of dtg -> 8-dim feature in-lane -> s2/sd via
//           ror8-DPP + shfl_xor(16,32) -> wk in-register -> acc FMA.
//           Slot-tree (xor1/xor2/hmirror DPP) -> part[r][wave][dim].
//   GEMM  : thread=(h, j-half); W float4 straight from L2, each element
//           once per block; partials combined via dead dtg.
// 4 barriers; ~8.2 KB LDS.
__global__ __launch_bounds__(256, 6) void fused(
    const float* __restrict__ adj_time, const float* __restrict__ gc,
    const float* __restrict__ cur_time, const float* __restrict__ neigh_mask,
    const float* __restrict__ hist_feat, const float* __restrict__ hist_time,
    const float* __restrict__ t2v_w, const float* __restrict__ t2v_b,
    const float* __restrict__ node_w, const float* __restrict__ node_b,
    const float* __restrict__ att_w, const float* __restrict__ att_b,
    const float* __restrict__ weight,
    const int* __restrict__ targets, const int* __restrict__ neigh_idx,
    float* __restrict__ out)
{
    const int b0   = blockIdx.x * RPB;
    const int tid  = threadIdx.x;
    const int lane = tid & 63;
    const int wv   = tid >> 6;          // wave id 0..3

    __shared__ float4 dtg[RPB * KK];        // {dt, g, ts, m}; reused as prow   4 KB
    __shared__ float  stL[RPB];             // target att-dot per row
    __shared__ float  part[RPB][4][DD];     // per-(target,wave) agg partials   2 KB
    __shared__ float  tile[RPB * 256];      // feat4 rows                       2 KB

    const float t = cur_time[0];

    // ---- per-lane dim-octet parameters (VGPR-resident, loaded once) ----
    const int dg = lane >> 3;           // dim octet 0..7
    const int d0 = dg * 8;
    float pw[8], pb[8], nw[8], nb[8], aw[8];
    {
        float4 a0 = *(const float4*)(t2v_w + d0),  a1 = *(const float4*)(t2v_w + d0 + 4);
        float4 b0_ = *(const float4*)(t2v_b + d0), b1 = *(const float4*)(t2v_b + d0 + 4);
        float4 c0 = *(const float4*)(node_w + d0), c1 = *(const float4*)(node_w + d0 + 4);
        float4 e0 = *(const float4*)(node_b + d0), e1 = *(const float4*)(node_b + d0 + 4);
        float4 w0 = *(const float4*)(att_w + 64 + d0), w1 = *(const float4*)(att_w + 64 + d0 + 4);
        pw[0]=a0.x*INV2PI; pw[1]=a0.y*INV2PI; pw[2]=a0.z*INV2PI; pw[3]=a0.w*INV2PI;
        pw[4]=a1.x*INV2PI; pw[5]=a1.y*INV2PI; pw[6]=a1.z*INV2PI; pw[7]=a1.w*INV2PI;
        pb[0]=b0_.x*INV2PI; pb[1]=b0_.y*INV2PI; pb[2]=b0_.z*INV2PI; pb[3]=b0_.w*INV2PI;
        pb[4]=b1.x*INV2PI; pb[5]=b1.y*INV2PI; pb[6]=b1.z*INV2PI; pb[7]=b1.w*INV2PI;
        nw[0]=c0.x; nw[1]=c0.y; nw[2]=c0.z; nw[3]=c0.w; nw[4]=c1.x; nw[5]=c1.y; nw[6]=c1.z; nw[7]=c1.w;
        nb[0]=e0.x; nb[1]=e0.y; nb[2]=e0.z; nb[3]=e0.w; nb[4]=e1.x; nb[5]=e1.y; nb[6]=e1.z; nb[7]=e1.w;
        aw[0]=w0.x; aw[1]=w0.y; aw[2]=w0.z; aw[3]=w0.w; aw[4]=w1.x; aw[5]=w1.y; aw[6]=w1.z; aw[7]=w1.w;
    }
    const float ow0 = t2v_w[0], ob0 = t2v_b[0];     // unscaled linear channel
    const float ab  = att_b[0];
    const bool  isd0 = (dg == 0);

    // ---- gathers: one slot per thread (slot = r*128 + k = tid) ----
    {
        const int   idx = neigh_idx[b0 * KK + tid];
        const float m   = neigh_mask[b0 * KK + tid];
        const float at  = adj_time[idx];
        const float g   = gc[idx];
        const float dt  = fabsf(t - at);
        const float ts  = fast_rcp(2.0f * __logf(2.71828182845904523536f + (t - at)));
        dtg[tid] = make_float4(dt, g, ts, m);
    }

    // ---- history aggregation, wave 3, fully self-contained ----
    if (wv == 3) {
        const int r  = lane >> 5;        // 0..1
        const int c4 = lane & 31;        // float4 column
        const float*  ht = hist_time + (size_t)(b0 + r) * WW;
        const float4* hf = (const float4*)(hist_feat + (size_t)(b0 + r) * WW * 128) + c4;
        float4 s4 = make_float4(0.f, 0.f, 0.f, 0.f);
#pragma unroll 4
        for (int w = 0; w < WW; ++w) {
            float  hw = fast_rcp(2.0f * (1.0f + (t - ht[w])));
            float4 v  = hf[w * 32];
            s4.x = fmaf(hw, v.x, s4.x);
            s4.y = fmaf(hw, v.y, s4.y);
            s4.z = fmaf(hw, v.z, s4.z);
            s4.w = fmaf(hw, v.w, s4.w);
        }
        *(float4*)(tile + r * 256 + c4 * 4) = s4;
    }

    // ---- target encoding, wave wv -> target wv (waves 0-1) ----
    if (wv < RPB) {
        int   tg  = targets[b0 + wv];
        float dtT = fabsf(t - adj_time[tg]);
        float gT  = gc[tg];
        float ph  = fmaf(t2v_w[lane], dtT, t2v_b[lane]);
        float cv  = __builtin_amdgcn_cosf(ph * INV2PI);
        float tv_ = (lane == 0) ? ph : cv;
        float f   = fmaxf(tv_ + fmaf(gT, node_w[lane], node_b[lane]), 0.f);
        float ss  = f * f;
#pragma unroll
        for (int off = 32; off; off >>= 1) ss += __shfl_xor(ss, off, 64);
        float invn = fast_rsq(fmaxf(ss, 1e-24f));
        float tfn  = f * invn;
        float sdt  = tfn * att_w[lane];
#pragma unroll
        for (int off = 32; off; off >>= 1) sdt += __shfl_xor(sdt, off, 64);
        if (lane == 0) stL[wv] = sdt;
        tile[wv * 256 + 128 + lane] = tfn;
    }
    __syncthreads();   // A: dtg, stL, hist tile cols ready

    // ---- core: score + aggregation, zero memory in the hot path ----
#pragma unroll
    for (int r = 0; r < RPB; ++r) {
        const float stv = stL[r];                   // uniform broadcast, once/target
        float acc[8] = {0.f, 0.f, 0.f, 0.f, 0.f, 0.f, 0.f, 0.f};
#pragma unroll
        for (int pass = 0; pass < 4; ++pass) {
            const float4 dgw = dtg[r * KK + pass * 32 + wv * 8 + (lane & 7)];
            const float dts = dgw.x, gs = dgw.y, tss = dgw.z, ms = dgw.w;
            float f[8], s2, sd;
            {   // i = 0 (handles the d==0 linear channel on dg==0 lanes)
                float ph  = fmaf(pw[0], dts, pb[0]);
                float cv  = __builtin_amdgcn_cosf(ph);
                float lin = fmaf(ow0, dts, ob0);
                float tv_ = isd0 ? lin : cv;
                float fv  = fmaxf(tv_ + fmaf(gs, nw[0], nb[0]), 0.f);
                f[0] = fv; s2 = fv * fv; sd = fv * aw[0];
            }
#pragma unroll
            for (int i = 1; i < 8; ++i) {
                float ph = fmaf(pw[i], dts, pb[i]);
                float cv = __builtin_amdgcn_cosf(ph);
                float fv = fmaxf(cv + fmaf(gs, nw[i], nb[i]), 0.f);
                f[i] = fv;
                s2 = fmaf(fv, fv, s2);
                sd = fmaf(fv, aw[i], sd);
            }
            // reduce s2/sd over the 8 dim-octets (stride-8 lanes)
            s2 = dpp_add<DPP_ROR8>(s2);
            s2 += __shfl_xor(s2, 16, 64);
            s2 += __shfl_xor(s2, 32, 64);
            sd = dpp_add<DPP_ROR8>(sd);
            sd += __shfl_xor(sd, 16, 64);
            sd += __shfl_xor(sd, 32, 64);
            // wk fully in-register
            float invn = fast_rsq(fmaxf(s2, 1e-24f));
            float sc   = tss + stv + sd * invn + ab;
            sc = (sc > 0.f) ? sc : 0.01f * sc;      // leaky_relu(0.01)
            float wk = sc * ms * invn;
#pragma unroll
            for (int i = 0; i < 8; ++i) acc[i] = fmaf(wk, f[i], acc[i]);
        }
        // slot-tree: sum over 8 consecutive lanes (the 8 slot positions)
#pragma unroll
        for (int i = 0; i < 8; ++i) {
            acc[i] = dpp_add<DPP_XOR1>(acc[i]);
            acc[i] = dpp_add<DPP_XOR2>(acc[i]);
            acc[i] = dpp_add<DPP_HMIRR>(acc[i]);
        }
        if ((lane & 7) == 0) {
#pragma unroll
            for (int i = 0; i < 8; ++i) part[r][wv][d0 + i] = acc[i];
        }
    }
    __syncthreads();   // D: partials ready; dtg dead

    // ---- combine: tile cols 192-255 = sum of 4 wave partials ----
    if (tid < RPB * DD) {
        const int r = tid >> 6, d = tid & 63;
        float s = part[r][0][d] + part[r][1][d] + part[r][2][d] + part[r][3][d];
        tile[r * 256 + 192 + d] = s;
    }
    __syncthreads();   // E: tile complete

    // ---- GEMM: thread = (h, j-half sq); W float4 straight from L2 ----
    const int h  = tid & 127;
    const int sq = tid >> 7;                        // 0..1
    const float4* w4 = (const float4*)weight + h * 64 + sq * 32;
    const int jb = sq * 128;
    float a0 = 0.f, a1 = 0.f;
#pragma unroll 4
    for (int j4 = 0; j4 < 32; ++j4) {
        float4 w  = w4[j4];
        const int jo = jb + j4 * 4;
        float4 f0 = *(const float4*)(tile + 0 * 256 + jo);   // uniform broadcasts
        float4 f1 = *(const float4*)(tile + 1 * 256 + jo);
        a0 += w.x * f0.x + w.y * f0.y + w.z * f0.z + w.w * f0.w;
        a1 += w.x * f1.x + w.y * f1.y + w.z * f1.z + w.w * f1.w;
    }

    // ---- combine 2 sq-partials per (row, h) via dead dtg buffer ----
    float* prow = (float*)dtg;                      // 1024 floats
    prow[(0 * 2 + sq) * 128 + h] = a0;
    prow[(1 * 2 + sq) * 128 + h] = a1;
    __syncthreads();   // F
    {
        const int r2 = tid >> 7;                    // 0..1
        float s = prow[(r2 * 2 + 0) * 128 + h] + prow[(r2 * 2 + 1) * 128 + h];
        out[(size_t)(b0 + r2) * 128 + h] = fmaxf(s, 0.f);
    }
}

extern "C" void kernel_launch(void* const* d_in, const int* in_sizes, int n_in,
                              void* d_out, int out_size, void* d_ws, size_t ws_size,
                              hipStream_t stream) {
    const float* adj_time  = (const float*)d_in[0];
    const float* gc        = (const float*)d_in[1];
    const float* cur_time  = (const float*)d_in[2];
    const float* neigh_mask= (const float*)d_in[3];
    const float* hist_feat = (const float*)d_in[4];
    const float* hist_time = (const float*)d_in[5];
    const float* t2v_w     = (const float*)d_in[6];
    const float* t2v_b     = (const float*)d_in[7];
    const float* node_w    = (const float*)d_in[8];
    const float* node_b    = (const float*)d_in[9];
    const float* att_w     = (const float*)d_in[10];
    const float* att_b     = (const float*)d_in[11];
    const float* weight    = (const float*)d_in[12];
    const int*   targets   = (const int*)d_in[13];
    const int*   neigh_idx = (const int*)d_in[14];

    float* out = (float*)d_out;

    fused<<<BB / RPB, TPB, 0, stream>>>(adj_time, gc, cur_time, neigh_mask,
                                        hist_feat, hist_time, t2v_w, t2v_b,
                                        node_w, node_b, att_w, att_b, weight,
                                        targets, neigh_idx, out);
}

// Round 10
// 146.249 us; speedup vs baseline: 1.6029x; 1.1336x over previous
//
#include <hip/hip_runtime.h>
#include <math.h>

#define NN 200000
#define DD 64
#define BB 4096
#define KK 128
#define WW 20
#define HH 128
#define TPB 256
#define RPB 2    // targets per block; 4 waves/block, 8 blocks/CU

#define INV2PI 0.15915494309189535f

__device__ __forceinline__ float fast_rcp(float x) { return __builtin_amdgcn_rcpf(x); }
__device__ __forceinline__ float fast_rsq(float x) { return __builtin_amdgcn_rsqf(x); }

// Round 10 = the VERIFIED R3/R6 core (42.4 us, 28 VGPR, no spill) with ONLY
// the synchronization domain halved: 2048 blocks x 256 threads (4 waves),
// 2 targets/block, 8 independent blocks/CU. R8/R9 tried this test with the
// param-in-VGPR core and measured register spill instead; R3's s_load-param
// core fits the (256,8) 64-VGPR cap with 2x headroom.
//   start : gathers (1 slot/thread) -> dtg{dt,g,-,-}; wave 3 runs the whole
//           history aggregation; waves 0-1 target encodings -> stL + tile.
//   partA : 64-dim feature norm+att dot in-lane (unroll 4, s_load params)
//           before barrier A.
//   partB : finish score with stL, write wk -> dtg.z.
//   phase3: wave pair (2r,2r+1) owns target r; lane=dim; 64 uniform b128
//           broadcasts; partials combined via p3p.
//   GEMM  : thread=(h, j-half) reads W float4 straight from L2; tile rows
//           via uniform LDS broadcasts; partials combined through dead dtg.
// 6 block barriers, each coupling only 4 waves; ~6.6 KB LDS.
__global__ __launch_bounds__(256, 8) void fused(
    const float* __restrict__ adj_time, const float* __restrict__ gc,
    const float* __restrict__ cur_time, const float* __restrict__ neigh_mask,
    const float* __restrict__ hist_feat, const float* __restrict__ hist_time,
    const float* __restrict__ t2v_w, const float* __restrict__ t2v_b,
    const float* __restrict__ node_w, const float* __restrict__ node_b,
    const float* __restrict__ att_w, const float* __restrict__ att_b,
    const float* __restrict__ weight,
    const int* __restrict__ targets, const int* __restrict__ neigh_idx,
    float* __restrict__ out)
{
    const int b0   = blockIdx.x * RPB;
    const int tid  = threadIdx.x;
    const int lane = tid & 63;
    const int wv   = tid >> 6;          // wave id 0..3

    __shared__ float4 dtg[RPB * KK];    // {dt, g, wk, -}; reused as prow    4 KB
    __shared__ float  stL[RPB];         // target att-dot per row
    __shared__ float  p3p[RPB][DD];     // phase-3 odd-wave partials        512 B
    __shared__ float  tile[RPB * 256];  // feat4 rows                        2 KB

    const float t = cur_time[0];

    // ---- gathers: one slot per thread (slot = r*128 + k = tid) ----
    const int   slot = tid;
    const int   idx  = neigh_idx[b0 * KK + slot];
    const float m    = neigh_mask[b0 * KK + slot];
    const float at   = adj_time[idx];
    const float g    = gc[idx];
    const float dt   = fabsf(t - at);
    const float ts   = fast_rcp(2.0f * __logf(2.71828182845904523536f + (t - at)));
    dtg[slot] = make_float4(dt, g, 0.f, 0.f);

    // ---- history aggregation, wave 3, fully self-contained ----
    if (wv == 3) {
        const int r  = lane >> 5;        // 0..1
        const int c4 = lane & 31;        // float4 column
        const float*  ht = hist_time + (size_t)(b0 + r) * WW;
        const float4* hf = (const float4*)(hist_feat + (size_t)(b0 + r) * WW * 128) + c4;
        float4 s4 = make_float4(0.f, 0.f, 0.f, 0.f);
#pragma unroll 4
        for (int w = 0; w < WW; ++w) {
            float  hw = fast_rcp(2.0f * (1.0f + (t - ht[w])));
            float4 v  = hf[w * 32];
            s4.x = fmaf(hw, v.x, s4.x);
            s4.y = fmaf(hw, v.y, s4.y);
            s4.z = fmaf(hw, v.z, s4.z);
            s4.w = fmaf(hw, v.w, s4.w);
        }
        *(float4*)(tile + r * 256 + c4 * 4) = s4;
    }

    // ---- target encoding, wave wv -> target wv (waves 0-1) ----
    if (wv < RPB) {
        int   tg  = targets[b0 + wv];
        float dtT = fabsf(t - adj_time[tg]);
        float gT  = gc[tg];
        float ph  = fmaf(t2v_w[lane], dtT, t2v_b[lane]);
        float cv  = __builtin_amdgcn_cosf(ph * INV2PI);   // bounded v_mul+v_cos
        float tv_ = (lane == 0) ? ph : cv;
        float f   = fmaxf(tv_ + fmaf(gT, node_w[lane], node_b[lane]), 0.f);
        float ss  = f * f;
#pragma unroll
        for (int off = 32; off; off >>= 1) ss += __shfl_xor(ss, off, 64);
        float invn = fast_rsq(fmaxf(ss, 1e-24f));
        float tfn  = f * invn;
        float sdt  = tfn * att_w[lane];
#pragma unroll
        for (int off = 32; off; off >>= 1) sdt += __shfl_xor(sdt, off, 64);
        if (lane == 0) stL[wv] = sdt;
        tile[wv * 256 + 128 + lane] = tfn;
    }

    // ---- part A: 64-dim in-lane norm+att from registers (no LDS deps) ----
    float s2, sd;
    {
        {   // d = 0: linear channel (no cos)
            float ph = fmaf(t2v_w[0], dt, t2v_b[0]);
            float f  = fmaxf(ph + fmaf(g, node_w[0], node_b[0]), 0.f);
            s2 = f * f;
            sd = f * att_w[64];
        }
#pragma unroll 4
        for (int d = 1; d < 64; ++d) {
            float ph = fmaf(t2v_w[d], dt, t2v_b[d]);
            float cv = __builtin_amdgcn_cosf(ph * INV2PI);   // bounded v_mul+v_cos
            float f  = fmaxf(cv + fmaf(g, node_w[d], node_b[d]), 0.f);
            s2 = fmaf(f, f, s2);
            sd = fmaf(f, att_w[64 + d], sd);
        }
    }
    __syncthreads();   // A: stL ready (dtg.xy, hist tile writes also done)

    // ---- part B: finish score, write wk ----
    {
        float invn = fast_rsq(fmaxf(s2, 1e-24f));
        float sc   = ts + stL[slot >> 7] + sd * invn + att_b[0];
        sc = (sc > 0.f) ? sc : 0.01f * sc;          // leaky_relu(0.01)
        dtg[slot].z = sc * m * invn;                // packed wk
    }
    __syncthreads();   // C: wk ready

    // ---- phase 3: wave pair (2r, 2r+1) owns target r; lane = dim ----
    const int r3   = wv >> 1;           // 0..1
    const int half = wv & 1;
    float acc3 = 0.f;
    {
        float scn = (lane == 0) ? 1.f : INV2PI;     // lane 0 = linear channel
        float pw  = t2v_w[lane] * scn;
        float pb  = t2v_b[lane] * scn;
        float nw  = node_w[lane];
        float nb2 = node_b[lane];
        const int base = r3 * KK + half * 64;
#pragma unroll 4
        for (int k = 0; k < 64; ++k) {
            float4 dgw = dtg[base + k];             // uniform addr -> broadcast b128
            float  ph  = fmaf(pw, dgw.x, pb);
            float  cv  = __builtin_amdgcn_cosf(ph); // v_cos: cos(2*pi*ph)
            float  tv_ = lane ? cv : ph;
            float  f   = fmaxf(tv_ + fmaf(dgw.y, nw, nb2), 0.f);
            acc3 = fmaf(dgw.z, f, acc3);
        }
    }
    if (half) p3p[r3][lane] = acc3;
    __syncthreads();   // D: odd-wave partials ready; dtg dead after this point
    if (!half) tile[r3 * 256 + 192 + lane] = acc3 + p3p[r3][lane];
    __syncthreads();   // E: tile complete

    // ---- GEMM: thread = (h, j-half sq); W float4 straight from L2 ----
    const int h  = tid & 127;
    const int sq = tid >> 7;                        // 0..1
    const float4* w4 = (const float4*)weight + h * 64 + sq * 32;
    const int jb = sq * 128;
    float a0 = 0.f, a1 = 0.f;
#pragma unroll 4
    for (int j4 = 0; j4 < 32; ++j4) {
        float4 w  = w4[j4];
        const int jo = jb + j4 * 4;
        float4 f0 = *(const float4*)(tile + 0 * 256 + jo);   // uniform broadcasts
        float4 f1 = *(const float4*)(tile + 1 * 256 + jo);
        a0 += w.x * f0.x + w.y * f0.y + w.z * f0.z + w.w * f0.w;
        a1 += w.x * f1.x + w.y * f1.y + w.z * f1.z + w.w * f1.w;
    }

    // ---- combine 2 sq-partials per (row, h) via dead dtg buffer ----
    float* prow = (float*)dtg;                      // 1024 floats
    prow[(0 * 2 + sq) * 128 + h] = a0;
    prow[(1 * 2 + sq) * 128 + h] = a1;
    __syncthreads();   // F
    {
        const int r2 = tid >> 7;                    // 0..1
        float s = prow[(r2 * 2 + 0) * 128 + h] + prow[(r2 * 2 + 1) * 128 + h];
        out[(size_t)(b0 + r2) * 128 + h] = fmaxf(s, 0.f);
    }
}

extern "C" void kernel_launch(void* const* d_in, const int* in_sizes, int n_in,
                              void* d_out, int out_size, void* d_ws, size_t ws_size,
                              hipStream_t stream) {
    const float* adj_time  = (const float*)d_in[0];
    const float* gc        = (const float*)d_in[1];
    const float* cur_time  = (const float*)d_in[2];
    const float* neigh_mask= (const float*)d_in[3];
    const float* hist_feat = (const float*)d_in[4];
    const float* hist_time = (const float*)d_in[5];
    const float* t2v_w     = (const float*)d_in[6];
    const float* t2v_b     = (const float*)d_in[7];
    const float* node_w    = (const float*)d_in[8];
    const float* node_b    = (const float*)d_in[9];
    const float* att_w     = (const float*)d_in[10];
    const float* att_b     = (const float*)d_in[11];
    const float* weight    = (const float*)d_in[12];
    const int*   targets   = (const int*)d_in[13];
    const int*   neigh_idx = (const int*)d_in[14];

    float* out = (float*)d_out;

    fused<<<BB / RPB, TPB, 0, stream>>>(adj_time, gc, cur_time, neigh_mask,
                                        hist_feat, hist_time, t2v_w, t2v_b,
                                        node_w, node_b, att_w, att_b, weight,
                                        targets, neigh_idx, out);
}